// Round 1
// baseline (651.907 us; speedup 1.0000x reference)
//
#include <hip/hip_runtime.h>
#include <hip/hip_bf16.h>
#include <float.h>

#define NF 75
#define HID 128
#define NB 50
#define NT 12
#define N_ATOMS_C 200000
#define BN_EPS 1e-3f

// Static device scratch (avoids depending on ws_size). Fully written before
// read on every launch -> no cross-call state.
__device__ float g_bn1[(size_t)N_ATOMS_C * HID];   // 102.4 MB
__device__ float g_part[8 * NB * 256];             // segment partials

struct AdjPtrs { const int* p[10]; };

// ---------------- K1: gc1 (gather + per-degree GEMM) + tanh + bn1 ----------------
// One block = 64 atoms of a single degree x all 128 output cols.
// LDS: A[64][160] (nbr_sum || self, zero-padded K->160), W chunk [32][128].
__global__ __launch_bounds__(256, 2) void k_gc1(
    const float* __restrict__ X, const float* __restrict__ W, const float* __restrict__ B,
    const float* __restrict__ bg, const float* __restrict__ bb,
    const float* __restrict__ bm, const float* __restrict__ bv,
    AdjPtrs adj)
{
    // tiles-of-64 per degree (compile-time layout)
    constexpr int TS[12] = {0,16,313,938,1876,2658,2893,3018,3081,3113,3124,3129};
    constexpr int DS[12] = {0,1000,20000,60000,120000,170000,185000,193000,197000,199000,199700,200000};

    __shared__ __align__(16) float A[64][160];
    __shared__ __align__(16) float Wb[32][128];

    const int blk = blockIdx.x;
    int deg = 0;
#pragma unroll
    for (int d = 1; d <= 10; ++d) if (blk >= TS[d]) deg = d;
    const int tile   = blk - TS[deg];
    const int dStart = DS[deg];
    const int dEnd   = DS[deg + 1];
    const int atom0  = dStart + tile * 64;
    const int nA     = min(64, dEnd - atom0);
    const int tid    = threadIdx.x;

    const int* __restrict__ adjBase = (deg > 0) ? adj.p[deg - 1] : nullptr;
    const float* __restrict__ W0 = W + (size_t)((deg > 0) ? 2 * (deg - 1) : 20) * NF * HID;
    const float* __restrict__ W1 = W0 + NF * HID;  // self-W (valid only for deg>0)

    // ---- fill A: cols [0,75)=nbr_sum, [75,150)=self, [150,160)=0 ----
    for (int idx = tid; idx < 64 * NF; idx += 256) {
        const int a = idx / NF;
        const int f = idx - a * NF;
        const int atom = atom0 + a;
        float sv = 0.f, nb = 0.f;
        if (a < nA) {
            sv = X[atom * NF + f];
            if (deg > 0) {
                const int* r = adjBase + (size_t)(atom - dStart) * deg;
                for (int j = 0; j < deg; ++j) nb += X[r[j] * NF + f];
            }
        }
        if (deg > 0) { A[a][f] = nb; A[a][NF + f] = sv; }
        else         { A[a][f] = sv; A[a][NF + f] = 0.f; }
    }
    for (int idx = tid; idx < 64 * 10; idx += 256) {
        const int a = idx / 10;
        const int f = idx - a * 10;
        A[a][150 + f] = 0.f;
    }

    // ---- GEMM: C[64][128] = A[64][160] @ Wcat[160][128] ----
    float acc[8][4] = {};
    const int c0 = (tid & 31) * 4;   // 4 consecutive cols
    const int a0 = (tid >> 5) * 8;   // 8 atoms

    for (int kb = 0; kb < 160; kb += 32) {
        __syncthreads();
        for (int idx = tid; idx < 32 * 128; idx += 256) {
            const int kk = idx >> 7;
            const int c  = idx & 127;
            const int k  = kb + kk;
            float wv = 0.f;
            if (k < NF) wv = W0[k * HID + c];
            else if (k < 2 * NF && deg > 0) wv = W1[(k - NF) * HID + c];
            Wb[kk][c] = wv;
        }
        __syncthreads();
#pragma unroll
        for (int kk = 0; kk < 32; kk += 4) {
            const float4 w0 = *(const float4*)&Wb[kk + 0][c0];
            const float4 w1 = *(const float4*)&Wb[kk + 1][c0];
            const float4 w2 = *(const float4*)&Wb[kk + 2][c0];
            const float4 w3 = *(const float4*)&Wb[kk + 3][c0];
#pragma unroll
            for (int i = 0; i < 8; ++i) {
                const float4 av = *(const float4*)&A[a0 + i][kb + kk];
                acc[i][0] = fmaf(av.w, w3.x, fmaf(av.z, w2.x, fmaf(av.y, w1.x, fmaf(av.x, w0.x, acc[i][0]))));
                acc[i][1] = fmaf(av.w, w3.y, fmaf(av.z, w2.y, fmaf(av.y, w1.y, fmaf(av.x, w0.y, acc[i][1]))));
                acc[i][2] = fmaf(av.w, w3.z, fmaf(av.z, w2.z, fmaf(av.y, w1.z, fmaf(av.x, w0.z, acc[i][2]))));
                acc[i][3] = fmaf(av.w, w3.w, fmaf(av.z, w2.w, fmaf(av.y, w1.w, fmaf(av.x, w0.w, acc[i][3]))));
            }
        }
    }

    // ---- epilogue: +bias, tanh, batchnorm, store bn1 ----
    float bias[4], sc[4], sh[4];
#pragma unroll
    for (int j = 0; j < 4; ++j) {
        const int c = c0 + j;
        float bsum;
        if (deg > 0) {
            const float* br = B + 2 * (deg - 1) * HID;
            bsum = br[c] + br[HID + c];
        } else {
            bsum = B[20 * HID + c];
        }
        bias[j] = bsum;
        const float s = bg[c] * rsqrtf(bv[c] + BN_EPS);
        sc[j] = s;
        sh[j] = bb[c] - bm[c] * s;
    }
#pragma unroll
    for (int i = 0; i < 8; ++i) {
        if (a0 + i < nA) {
            float4 r;
            r.x = tanhf(acc[i][0] + bias[0]) * sc[0] + sh[0];
            r.y = tanhf(acc[i][1] + bias[1]) * sc[1] + sh[1];
            r.z = tanhf(acc[i][2] + bias[2]) * sc[2] + sh[2];
            r.w = tanhf(acc[i][3] + bias[3]) * sc[3] + sh[3];
            *(float4*)&g_bn1[(size_t)(atom0 + a0 + i) * HID + c0] = r;
        }
    }
}

// ---------------- K2: deterministic segment sum/max partials ----------------
// Block = (segment s in 0..7) x (batch b in 0..49); 2 waves; each wave compacts
// its own matched-atom queue via ballot (deterministic order), cols split by wave.
__global__ __launch_bounds__(128) void k_seg(const int* __restrict__ memb)
{
    const int b = blockIdx.x % NB;
    const int s = blockIdx.x / NB;
    const int aLo = s * (N_ATOMS_C / 8);
    const int aHi = aLo + (N_ATOMS_C / 8);
    const int wave = threadIdx.x >> 6;
    const int lane = threadIdx.x & 63;

    __shared__ int q[2][1024];
    int* myq = q[wave];
    int nq = 0;

    for (int base = aLo; base < aHi; base += 64) {
        const int a = base + lane;
        const bool m = (a < aHi) && (memb[a] == b);
        const unsigned long long bal = __ballot(m);
        if (m) {
            const int pos = __popcll(bal & ((1ull << lane) - 1ull));
            if (nq + pos < 1024) myq[nq + pos] = a;
        }
        nq += __popcll(bal);
    }
    if (nq > 1024) nq = 1024;  // statistically impossible; safety only
    __syncthreads();

    const int c = threadIdx.x;  // col 0..127
    float sum = 0.f, mx = -FLT_MAX;
    for (int i = 0; i < nq; ++i) {
        const float v = g_bn1[(size_t)myq[i] * HID + c];
        sum += v;
        mx = fmaxf(mx, v);
    }
    float* pd = g_part + (size_t)(s * NB + b) * 256;
    pd[c] = sum;
    pd[128 + c] = mx;
}

// ---------------- K3: reduce partials, tanh, dense [256,24], softmax pairs ----------------
__global__ __launch_bounds__(256) void k_final(const float* __restrict__ W2,
                                               const float* __restrict__ b2,
                                               float* __restrict__ out)
{
    const int b = blockIdx.x;
    const int t = threadIdx.x;
    __shared__ float ro[256];
    __shared__ float lg[24];

    {
        float v;
        if (t < 128) {
            float sv = 0.f;
#pragma unroll
            for (int s = 0; s < 8; ++s) sv += g_part[(size_t)(s * NB + b) * 256 + t];
            v = sv;
        } else {
            float mv = -FLT_MAX;
#pragma unroll
            for (int s = 0; s < 8; ++s) mv = fmaxf(mv, g_part[(size_t)(s * NB + b) * 256 + t]);
            v = mv;
        }
        ro[t] = tanhf(v);
    }
    __syncthreads();
    if (t < 24) {
        float acc = b2[t];
        for (int c = 0; c < 256; ++c) acc = fmaf(ro[c], W2[c * 24 + t], acc);
        lg[t] = acc;
    }
    __syncthreads();
    if (t < NT) {
        const float l0 = lg[2 * t], l1 = lg[2 * t + 1];
        const float m = fmaxf(l0, l1);
        const float e0 = expf(l0 - m), e1 = expf(l1 - m);
        const float inv = 1.f / (e0 + e1);
        out[b * 24 + 2 * t]     = e0 * inv;
        out[b * 24 + 2 * t + 1] = e1 * inv;
    }
}

extern "C" void kernel_launch(void* const* d_in, const int* in_sizes, int n_in,
                              void* d_out, int out_size, void* d_ws, size_t ws_size,
                              hipStream_t stream) {
    const float* X    = (const float*)d_in[0];
    const int*   memb = (const int*)d_in[2];
    AdjPtrs adj;
    for (int d = 0; d < 10; ++d) adj.p[d] = (const int*)d_in[3 + d];
    const float* W1 = (const float*)d_in[13];
    const float* B1 = (const float*)d_in[14];
    const float* bg = (const float*)d_in[17];
    const float* bb = (const float*)d_in[18];
    const float* bm = (const float*)d_in[19];
    const float* bv = (const float*)d_in[20];
    const float* W2 = (const float*)d_in[31];
    const float* b2 = (const float*)d_in[32];
    float* out = (float*)d_out;

    k_gc1<<<3129, 256, 0, stream>>>(X, W1, B1, bg, bb, bm, bv, adj);
    k_seg<<<400, 128, 0, stream>>>(memb);
    k_final<<<50, 256, 0, stream>>>(W2, b2, out);
}

// Round 2
// 238.252 us; speedup vs baseline: 2.7362x; 2.7362x over previous
//
#include <hip/hip_runtime.h>
#include <hip/hip_bf16.h>
#include <float.h>

#define NF 75
#define HID 128
#define NB 50
#define NT 12
#define N_ATOMS_C 200000
#define BN_EPS 1e-3f
#define NSEG 16

// Static device scratch. Fully written before read on every launch.
__device__ float g_bn1[(size_t)N_ATOMS_C * HID];   // 102.4 MB
__device__ float g_part[NSEG * NB * 256];          // segment partials

struct AdjPtrs { const int* p[10]; };

__device__ __forceinline__ float fast_tanh(float x) {
    // tanh(x) = 1 - 2/(e^{2x}+1); __expf -> v_exp_f32. Saturates correctly.
    float e = __expf(2.f * x);
    return 1.f - 2.f / (e + 1.f);
}

// Degree layout (compile-time)
__device__ constexpr int DS_[12] = {0,1000,20000,60000,120000,170000,185000,193000,197000,199000,199700,200000};

// ---------------- gc1 body: gather + GEMM + tanh + bn1 ----------------
// Block: 256 threads, 64 atoms of one degree, all 128 cols.
// LDS: A[64][160] f32. cols 0..74 nbr_sum, 75..149 self (deg>0), 150..159 adj stash.
template<int DEG>
__device__ __forceinline__ void gc1_body(
    int tile, float* __restrict__ A,
    const float* __restrict__ X, const float* __restrict__ W, const float* __restrict__ B,
    const float* __restrict__ bg, const float* __restrict__ bb,
    const float* __restrict__ bm, const float* __restrict__ bv,
    const int* __restrict__ adjBase)
{
    const int dStart = DS_[DEG], dEnd = DS_[DEG + 1];
    const int atom0  = dStart + tile * 64;
    const int nA     = min(64, dEnd - atom0);
    const int tid    = threadIdx.x;
    constexpr int K  = (DEG > 0) ? 150 : 75;
    const float* __restrict__ W0 = W + (size_t)((DEG > 0) ? 2 * (DEG - 1) : 20) * NF * HID;

    // ---- stash adjacency rows in A[a][150+j] ----
    if (DEG > 0) {
        for (int idx = tid; idx < 64 * DEG; idx += 256) {
            const int a = idx / DEG, j = idx - a * DEG;
            int v = 0;
            if (a < nA) v = adjBase[(size_t)(atom0 + a - dStart) * DEG + j];
            A[a * 160 + 150 + j] = __int_as_float(v);
        }
        __syncthreads();
    }

    // ---- stage A: f-major mapping (coalesced X reads, conflict-free LDS writes) ----
    for (int idx = tid; idx < 64 * 76; idx += 256) {
        const int a = idx / 76, f = idx - a * 76;
        if (f < 75 && a < nA) {
            const float slf = X[(size_t)(atom0 + a) * NF + f];
            if (DEG > 0) {
                float nb = 0.f;
#pragma unroll
                for (int j = 0; j < DEG; ++j) {
                    const int r = __float_as_int(A[a * 160 + 150 + j]);
                    nb += X[(size_t)r * NF + f];
                }
                A[a * 160 + f]      = nb;
                A[a * 160 + 75 + f] = slf;
            } else {
                A[a * 160 + f] = slf;
            }
        }
    }
    __syncthreads();

    // ---- GEMM: C[64][128] = A[64][K] @ W0[K][128]; W streamed from L1/L2 ----
    float acc[8][4] = {};
    const int c0 = (tid & 31) * 4;   // 4 consecutive cols
    const int a0 = (tid >> 5) * 8;   // 8 atoms
    constexpr int K4 = K & ~3;

    for (int kb = 0; kb < K4; kb += 4) {
        const float4 w0 = *(const float4*)(W0 + (size_t)(kb + 0) * HID + c0);
        const float4 w1 = *(const float4*)(W0 + (size_t)(kb + 1) * HID + c0);
        const float4 w2 = *(const float4*)(W0 + (size_t)(kb + 2) * HID + c0);
        const float4 w3 = *(const float4*)(W0 + (size_t)(kb + 3) * HID + c0);
#pragma unroll
        for (int i = 0; i < 8; ++i) {
            const float4 av = *(const float4*)&A[(a0 + i) * 160 + kb];
            acc[i][0] = fmaf(av.w, w3.x, fmaf(av.z, w2.x, fmaf(av.y, w1.x, fmaf(av.x, w0.x, acc[i][0]))));
            acc[i][1] = fmaf(av.w, w3.y, fmaf(av.z, w2.y, fmaf(av.y, w1.y, fmaf(av.x, w0.y, acc[i][1]))));
            acc[i][2] = fmaf(av.w, w3.z, fmaf(av.z, w2.z, fmaf(av.y, w1.z, fmaf(av.x, w0.z, acc[i][2]))));
            acc[i][3] = fmaf(av.w, w3.w, fmaf(av.z, w2.w, fmaf(av.y, w1.w, fmaf(av.x, w0.w, acc[i][3]))));
        }
    }
#pragma unroll
    for (int kb = K4; kb < K; ++kb) {
        const float4 w = *(const float4*)(W0 + (size_t)kb * HID + c0);
#pragma unroll
        for (int i = 0; i < 8; ++i) {
            const float av = A[(a0 + i) * 160 + kb];
            acc[i][0] = fmaf(av, w.x, acc[i][0]);
            acc[i][1] = fmaf(av, w.y, acc[i][1]);
            acc[i][2] = fmaf(av, w.z, acc[i][2]);
            acc[i][3] = fmaf(av, w.w, acc[i][3]);
        }
    }

    // ---- epilogue: +bias, tanh, batchnorm, store ----
    float bias[4], sc[4], sh[4];
#pragma unroll
    for (int j = 0; j < 4; ++j) {
        const int c = c0 + j;
        float bsum;
        if (DEG > 0) {
            const float* br = B + 2 * (DEG - 1) * HID;
            bsum = br[c] + br[HID + c];
        } else {
            bsum = B[20 * HID + c];
        }
        bias[j] = bsum;
        const float s = bg[c] * rsqrtf(bv[c] + BN_EPS);
        sc[j] = s;
        sh[j] = bb[c] - bm[c] * s;
    }
#pragma unroll
    for (int i = 0; i < 8; ++i) {
        if (a0 + i < nA) {
            float4 r;
            r.x = fast_tanh(acc[i][0] + bias[0]) * sc[0] + sh[0];
            r.y = fast_tanh(acc[i][1] + bias[1]) * sc[1] + sh[1];
            r.z = fast_tanh(acc[i][2] + bias[2]) * sc[2] + sh[2];
            r.w = fast_tanh(acc[i][3] + bias[3]) * sc[3] + sh[3];
            *(float4*)&g_bn1[(size_t)(atom0 + a0 + i) * HID + c0] = r;
        }
    }
}

__global__ __launch_bounds__(256, 4) void k_gc1(
    const float* __restrict__ X, const float* __restrict__ W, const float* __restrict__ B,
    const float* __restrict__ bg, const float* __restrict__ bb,
    const float* __restrict__ bm, const float* __restrict__ bv,
    AdjPtrs adj)
{
    constexpr int TS[12] = {0,16,313,938,1876,2658,2893,3018,3081,3113,3124,3129};
    __shared__ __align__(16) float A[64 * 160];   // 40 KB -> 4 blocks/CU

    const int blk = blockIdx.x;
    int deg = 0;
#pragma unroll
    for (int d = 1; d <= 10; ++d) if (blk >= TS[d]) deg = d;
    const int tile = blk - TS[deg];

    switch (deg) {
        case 0:  gc1_body<0 >(tile, A, X, W, B, bg, bb, bm, bv, nullptr);   break;
        case 1:  gc1_body<1 >(tile, A, X, W, B, bg, bb, bm, bv, adj.p[0]);  break;
        case 2:  gc1_body<2 >(tile, A, X, W, B, bg, bb, bm, bv, adj.p[1]);  break;
        case 3:  gc1_body<3 >(tile, A, X, W, B, bg, bb, bm, bv, adj.p[2]);  break;
        case 4:  gc1_body<4 >(tile, A, X, W, B, bg, bb, bm, bv, adj.p[3]);  break;
        case 5:  gc1_body<5 >(tile, A, X, W, B, bg, bb, bm, bv, adj.p[4]);  break;
        case 6:  gc1_body<6 >(tile, A, X, W, B, bg, bb, bm, bv, adj.p[5]);  break;
        case 7:  gc1_body<7 >(tile, A, X, W, B, bg, bb, bm, bv, adj.p[6]);  break;
        case 8:  gc1_body<8 >(tile, A, X, W, B, bg, bb, bm, bv, adj.p[7]);  break;
        case 9:  gc1_body<9 >(tile, A, X, W, B, bg, bb, bm, bv, adj.p[8]);  break;
        case 10: gc1_body<10>(tile, A, X, W, B, bg, bb, bm, bv, adj.p[9]);  break;
    }
}

// ---------------- K2: deterministic segment sum/max partials ----------------
__global__ __launch_bounds__(128) void k_seg(const int* __restrict__ memb)
{
    const int b = blockIdx.x % NB;
    const int s = blockIdx.x / NB;
    const int aLo = s * (N_ATOMS_C / NSEG);
    const int aHi = aLo + (N_ATOMS_C / NSEG);
    const int wave = threadIdx.x >> 6;
    const int lane = threadIdx.x & 63;

    __shared__ int q[2][1024];
    int* myq = q[wave];
    int nq = 0;

    for (int base = aLo; base < aHi; base += 64) {
        const int a = base + lane;
        const bool m = (a < aHi) && (memb[a] == b);
        const unsigned long long bal = __ballot(m);
        if (m) {
            const int pos = __popcll(bal & ((1ull << lane) - 1ull));
            if (nq + pos < 1024) myq[nq + pos] = a;
        }
        nq += __popcll(bal);
    }
    if (nq > 1024) nq = 1024;
    __syncthreads();

    const int c = threadIdx.x;  // col 0..127
    float sum = 0.f, mx = -FLT_MAX;
    for (int i = 0; i < nq; ++i) {
        const float v = g_bn1[(size_t)myq[i] * HID + c];
        sum += v;
        mx = fmaxf(mx, v);
    }
    float* pd = g_part + (size_t)(s * NB + b) * 256;
    pd[c] = sum;
    pd[128 + c] = mx;
}

// ---------------- K3: reduce partials, tanh, dense [256,24], softmax pairs ----------------
__global__ __launch_bounds__(256) void k_final(const float* __restrict__ W2,
                                               const float* __restrict__ b2,
                                               float* __restrict__ out)
{
    const int b = blockIdx.x;
    const int t = threadIdx.x;
    __shared__ float ro[256];
    __shared__ float lg[24];

    {
        float v;
        if (t < 128) {
            float sv = 0.f;
#pragma unroll
            for (int s = 0; s < NSEG; ++s) sv += g_part[(size_t)(s * NB + b) * 256 + t];
            v = sv;
        } else {
            float mv = -FLT_MAX;
#pragma unroll
            for (int s = 0; s < NSEG; ++s) mv = fmaxf(mv, g_part[(size_t)(s * NB + b) * 256 + t]);
            v = mv;
        }
        ro[t] = tanhf(v);
    }
    __syncthreads();
    if (t < 24) {
        float acc = b2[t];
        for (int c = 0; c < 256; ++c) acc = fmaf(ro[c], W2[c * 24 + t], acc);
        lg[t] = acc;
    }
    __syncthreads();
    if (t < NT) {
        const float l0 = lg[2 * t], l1 = lg[2 * t + 1];
        const float m = fmaxf(l0, l1);
        const float e0 = expf(l0 - m), e1 = expf(l1 - m);
        const float inv = 1.f / (e0 + e1);
        out[b * 24 + 2 * t]     = e0 * inv;
        out[b * 24 + 2 * t + 1] = e1 * inv;
    }
}

extern "C" void kernel_launch(void* const* d_in, const int* in_sizes, int n_in,
                              void* d_out, int out_size, void* d_ws, size_t ws_size,
                              hipStream_t stream) {
    const float* X    = (const float*)d_in[0];
    const int*   memb = (const int*)d_in[2];
    AdjPtrs adj;
    for (int d = 0; d < 10; ++d) adj.p[d] = (const int*)d_in[3 + d];
    const float* W1 = (const float*)d_in[13];
    const float* B1 = (const float*)d_in[14];
    const float* bg = (const float*)d_in[17];
    const float* bb = (const float*)d_in[18];
    const float* bm = (const float*)d_in[19];
    const float* bv = (const float*)d_in[20];
    const float* W2 = (const float*)d_in[31];
    const float* b2 = (const float*)d_in[32];
    float* out = (float*)d_out;

    k_gc1<<<3129, 256, 0, stream>>>(X, W1, B1, bg, bb, bm, bv, adj);
    k_seg<<<NSEG * NB, 128, 0, stream>>>(memb);
    k_final<<<NB, 256, 0, stream>>>(W2, b2, out);
}